// Round 7
// baseline (865.877 us; speedup 1.0000x reference)
//
#include <hip/hip_runtime.h>

// LSTM_52922587021316 — Round 7: layer-1 weights in block-shared LDS.
// R4/R6 lesson: streams/SIMD stuck at 4 because each wave privately holds
// 96 VGPRs of weight fragments. B1a/B1b (64 VGPR) move to one LDS copy per
// block (16 KB, staged once + one barrier); layer-1 loop re-reads fragments
// via ds_read_b128 (separate pipe, ~36us chip-wide < 60us trans floor).
// B0 stays in regs. One h-area per wave reused for both layers (same-wave
// DS is in-order). Cell state carried prescaled: cs = 2*log2e*c, with
// tanh_pre_g emitting 2L*tanh(g) via constant change (saves 1 mul/cell).
// launch_bounds(256,5): VGPR cap 102 -> >=5 waves/SIMD. Watch FETCH_SIZE:
// >>10 MB means the cap caused spills (R3/R5 signature) -> revert.

#define HID 32
#define TSTEPS 7
#define LSTRIDE 40   // halves per LDS h-row: 32 + 8 pad (80 B, 16B-aligned)

typedef _Float16 half8 __attribute__((ext_vector_type(8)));
typedef float floatx4 __attribute__((ext_vector_type(4)));

#define LOG2E 1.44269504088896f

__device__ __forceinline__ float fast_rcp(float x) { return __builtin_amdgcn_rcpf(x); }

__device__ __forceinline__ float exp2_fast(float x) {
#if __has_builtin(__builtin_amdgcn_exp2f)
    return __builtin_amdgcn_exp2f(x);
#else
    return __expf(x * 0.69314718055994531f);
#endif
}

// s = -x*log2e pre-applied via weight prescale
__device__ __forceinline__ float sigm_pre(float s) {
    return fast_rcp(1.0f + exp2_fast(s));
}
// s = 2x*log2e pre-applied; returns tanh(x)
__device__ __forceinline__ float tanh_pre(float s) {
    return fmaf(-2.0f, fast_rcp(exp2_fast(s) + 1.0f), 1.0f);
}
// s = 2x*log2e pre-applied; returns (2*log2e)*tanh(x)  [for prescaled cell]
__device__ __forceinline__ float tanh_pre_g(float s) {
    return fmaf(-4.0f * LOG2E, fast_rcp(exp2_fast(s) + 1.0f), 2.0f * LOG2E);
}

__global__ __launch_bounds__(256, 5) void lstm2_mfma(
    const float* __restrict__ xin,   // [B, 7]
    const float* __restrict__ Wih0,  // [128, 1]
    const float* __restrict__ Whh0,  // [128, 32]
    const float* __restrict__ bih0,  // [128]
    const float* __restrict__ bhh0,  // [128]
    const float* __restrict__ Wih1,  // [128, 32]
    const float* __restrict__ Whh1,  // [128, 32]
    const float* __restrict__ bih1,  // [128]
    const float* __restrict__ bhh1,  // [128]
    const float* __restrict__ fcw,   // [32]
    const float* __restrict__ fcb,   // [1]
    const float* __restrict__ fc1w,  // [7]
    const float* __restrict__ fc1b,  // [1]
    float* __restrict__ out,         // [B]
    int B)
{
    const int tid  = threadIdx.x;
    const int lane = tid & 63;
    const int wave = tid >> 6;
    const int col  = lane & 15;          // C col / A row m
    const int rg   = lane >> 4;          // C rows rg*4..+3 / A k-chunk rg*8..+7
    const int seq_base = (blockIdx.x * 4 + wave) * 16;

    // [mat][nt][lane][8 halves]: mat 0 = Wih1 (vs h1), 1 = Whh1 (vs h2)
    __shared__ __align__(16) _Float16 ldsW[2][8][64][8];      // 16384 B
    __shared__ __align__(16) _Float16 ldsh[4][16 * LSTRIDE];  //  5120 B
    __shared__ __align__(16) float    ldsx[4][TSTEPS * 16];   //  1792 B

    // ---- stage layer-1 weight fragments to LDS (block-shared, once) ------
    // frag element [nt][ln][j] = sc(n) * W[n = nt*16+(ln&15)][k = (ln>>4)*8+j]
#pragma unroll
    for (int f = 0; f < 2; ++f) {
        const int idx = tid * 2 + f;            // 0..511
        const int nt = idx >> 6, ln = idx & 63;
        const int n  = nt * 16 + (ln & 15);
        const int k0 = (ln >> 4) * 8;
        const float sc = ((n >> 5) == 2) ? (2.0f * LOG2E) : (-LOG2E);
        const float* sa = Wih1 + n * HID + k0;
        const float* sb = Whh1 + n * HID + k0;
        half8 fa, fb;
#pragma unroll
        for (int j = 0; j < 8; ++j) {
            fa[j] = (_Float16)(sc * sa[j]);
            fb[j] = (_Float16)(sc * sb[j]);
        }
        *(half8*)&ldsW[0][nt][ln][0] = fa;
        *(half8*)&ldsW[1][nt][ln][0] = fb;
    }

    // ---- stage x: 112 contiguous floats per wave -> transposed [t][m] ----
#pragma unroll
    for (int e = lane; e < TSTEPS * 16; e += 64) {
        const int s = e / TSTEPS;
        const int tt = e - s * TSTEPS;
        ldsx[wave][tt * 16 + s] = xin[seq_base * TSTEPS + e];
    }

    // ---- layer-0 weights stay in VGPRs (prescaled f16 B-fragments) -------
    half8 B0[8];
    float b0s[8], b1s[8], wx[8];
#pragma unroll
    for (int nt = 0; nt < 8; ++nt) {
        const int n = nt * 16 + col;
        const float sc = ((n >> 5) == 2) ? (2.0f * LOG2E) : (-LOG2E);
        const float* s0 = Whh0 + n * HID + rg * 8;
#pragma unroll
        for (int j = 0; j < 8; ++j) B0[nt][j] = (_Float16)(sc * s0[j]);
        b0s[nt] = sc * (bih0[n] + bhh0[n]);
        b1s[nt] = sc * (bih1[n] + bhh1[n]);
        wx[nt]  = sc * Wih0[n];
    }
    const float fcw_l0 = fcw[col];
    const float fcw_l1 = fcw[16 + col];

    __syncthreads();   // weight staging visible to all waves

    _Float16* hl = &ldsh[wave][0];       // one area, reused L0/L1 (in-order DS)

    half8 Ah1 = {};      // h1 in A-layout (zero at t=0)
    half8 Ah2 = {};      // h2 in A-layout
    float c1[2][4] = {}, c2[2][4] = {};  // prescaled: cs = 2*log2e*c
    float facc[4] = {0.f, 0.f, 0.f, 0.f};

#pragma unroll 1
    for (int t = 0; t < TSTEPS; ++t) {
        const floatx4 xr = *(const floatx4*)&ldsx[wave][t * 16 + rg * 4];

        // -------- layer 0: gates = (bias + x*Wih0) + h1_prev @ Whh0^T -----
        floatx4 g0[8];
#pragma unroll
        for (int nt = 0; nt < 8; ++nt) {
            floatx4 c;
#pragma unroll
            for (int r = 0; r < 4; ++r) c[r] = fmaf(wx[nt], xr[r], b0s[nt]);
            g0[nt] = __builtin_amdgcn_mfma_f32_16x16x32_f16(Ah1, B0[nt], c, 0, 0, 0);
        }

        // epilogue 0: cell update (prescaled cs), write h1_new to LDS
#pragma unroll
        for (int q = 0; q < 2; ++q) {
#pragma unroll
            for (int r = 0; r < 4; ++r) {
                const float ii = sigm_pre(g0[0 + q][r]);
                const float ff = sigm_pre(g0[2 + q][r]);
                const float gg = tanh_pre_g(g0[4 + q][r]);   // 2L*tanh(g)
                const float oo = sigm_pre(g0[6 + q][r]);
                const float cs = ff * c1[q][r] + ii * gg;    // = 2L*c
                c1[q][r] = cs;
                const float h = oo * tanh_pre(cs);           // tanh(c)
                hl[(rg * 4 + r) * LSTRIDE + q * 16 + col] = (_Float16)h;
            }
        }
        Ah1 = *(const half8*)&hl[col * LSTRIDE + rg * 8];

        // -------- layer 1: gates = bias + h1_new @ Wih1^T + h2_prev @ Whh1^T
        floatx4 g1[8];
#pragma unroll
        for (int nt = 0; nt < 8; ++nt) {
            const half8 fa = *(const half8*)&ldsW[0][nt][lane][0];
            const half8 fb = *(const half8*)&ldsW[1][nt][lane][0];
            floatx4 c = {b1s[nt], b1s[nt], b1s[nt], b1s[nt]};
            c = __builtin_amdgcn_mfma_f32_16x16x32_f16(Ah1, fa, c, 0, 0, 0);
            g1[nt] = __builtin_amdgcn_mfma_f32_16x16x32_f16(Ah2, fb, c, 0, 0, 0);
        }

        // epilogue 1: cell update, fc partial, write h2_new to LDS (same area)
        const float f1t = fc1w[t];
        const float w0 = f1t * fcw_l0;
        const float w1 = f1t * fcw_l1;
#pragma unroll
        for (int q = 0; q < 2; ++q) {
            const float wq = q ? w1 : w0;
#pragma unroll
            for (int r = 0; r < 4; ++r) {
                const float ii = sigm_pre(g1[0 + q][r]);
                const float ff = sigm_pre(g1[2 + q][r]);
                const float gg = tanh_pre_g(g1[4 + q][r]);
                const float oo = sigm_pre(g1[6 + q][r]);
                const float cs = ff * c2[q][r] + ii * gg;
                c2[q][r] = cs;
                const float h = oo * tanh_pre(cs);
                facc[r] = fmaf(wq, h, facc[r]);
                hl[(rg * 4 + r) * LSTRIDE + q * 16 + col] = (_Float16)h;
            }
        }
        Ah2 = *(const half8*)&hl[col * LSTRIDE + rg * 8];
    }

    // ---- reduce fc partials across the 16 cols, add constant tail --------
#pragma unroll
    for (int r = 0; r < 4; ++r) {
        float v = facc[r];
        v += __shfl_xor(v, 1);
        v += __shfl_xor(v, 2);
        v += __shfl_xor(v, 4);
        v += __shfl_xor(v, 8);
        facc[r] = v;
    }
    float sum_f1 = 0.f;
#pragma unroll
    for (int t = 0; t < TSTEPS; ++t) sum_f1 += fc1w[t];
    const float tail = fcb[0] * sum_f1 + fc1b[0];

    if (col == 0) {
#pragma unroll
        for (int r = 0; r < 4; ++r)
            out[seq_base + rg * 4 + r] = facc[r] + tail;
    }
}

extern "C" void kernel_launch(void* const* d_in, const int* in_sizes, int n_in,
                              void* d_out, int out_size, void* d_ws, size_t ws_size,
                              hipStream_t stream) {
    const float* xin  = (const float*)d_in[0];
    const float* Wih0 = (const float*)d_in[1];
    const float* Whh0 = (const float*)d_in[2];
    const float* bih0 = (const float*)d_in[3];
    const float* bhh0 = (const float*)d_in[4];
    const float* Wih1 = (const float*)d_in[5];
    const float* Whh1 = (const float*)d_in[6];
    const float* bih1 = (const float*)d_in[7];
    const float* bhh1 = (const float*)d_in[8];
    const float* fcw  = (const float*)d_in[9];
    const float* fcb  = (const float*)d_in[10];
    const float* fc1w = (const float*)d_in[11];
    const float* fc1b = (const float*)d_in[12];
    float* out = (float*)d_out;

    const int B = in_sizes[0] / TSTEPS;   // [B, T, F=1]
    const int grid = B / 64;              // 1 block = 4 waves = 64 sequences
    lstm2_mfma<<<grid, 256, 0, stream>>>(
        xin, Wih0, Whh0, bih0, bhh0, Wih1, Whh1, bih1, bhh1,
        fcw, fcb, fc1w, fc1b, out, B);
}

// Round 8
// 731.657 us; speedup vs baseline: 1.1834x; 1.1834x over previous
//
#include <hip/hip_runtime.h>

// LSTM_52922587021316 — Round 8: all weight matrices in block-shared LDS,
// under the proven-safe cap launch_bounds(256,4).
// Lessons: R3/R5/R7 — explicit tight bounds (or doubled state) make the
// allocator spill (FETCH_SIZE balloons to 100s of MB). R4 proved cap=128 is
// spill-free even WITH 96 VGPR of weights in regs. Here weights (Whh0, Wih1,
// Whh1 as prescaled f16 B-fragments) live in one 24 KB LDS copy per block;
// per-timestep reads are 24x ds_read_b128 (separate DS pipe, ~15us chip-
// wide). Natural VGPR pressure should land ~90-110 < 128 => no spill, and
// if <=102 the HW grants 5 waves/SIMD (vs R4's 4) for free.
// Also keeps R7's proven prescaled-cell (cs = 2*log2e*c, saves 1 mul/cell).
// Watch: VGPR_Count (<=102?), FETCH_SIZE (~4 MB = clean, >>10 MB = spill).

#define HID 32
#define TSTEPS 7
#define LSTRIDE 40   // halves per LDS h-row: 32 + 8 pad (80 B, 16B-aligned)

typedef _Float16 half8 __attribute__((ext_vector_type(8)));
typedef float floatx4 __attribute__((ext_vector_type(4)));

#define LOG2E 1.44269504088896f

__device__ __forceinline__ float fast_rcp(float x) { return __builtin_amdgcn_rcpf(x); }

__device__ __forceinline__ float exp2_fast(float x) {
#if __has_builtin(__builtin_amdgcn_exp2f)
    return __builtin_amdgcn_exp2f(x);
#else
    return __expf(x * 0.69314718055994531f);
#endif
}

// s = -x*log2e pre-applied via weight prescale
__device__ __forceinline__ float sigm_pre(float s) {
    return fast_rcp(1.0f + exp2_fast(s));
}
// s = 2x*log2e pre-applied; returns tanh(x)
__device__ __forceinline__ float tanh_pre(float s) {
    return fmaf(-2.0f, fast_rcp(exp2_fast(s) + 1.0f), 1.0f);
}
// s = 2x*log2e pre-applied; returns (2*log2e)*tanh(x)  [prescaled-cell form]
__device__ __forceinline__ float tanh_pre_g(float s) {
    return fmaf(-4.0f * LOG2E, fast_rcp(exp2_fast(s) + 1.0f), 2.0f * LOG2E);
}

__global__ __launch_bounds__(256, 4) void lstm2_mfma(
    const float* __restrict__ xin,   // [B, 7]
    const float* __restrict__ Wih0,  // [128, 1]
    const float* __restrict__ Whh0,  // [128, 32]
    const float* __restrict__ bih0,  // [128]
    const float* __restrict__ bhh0,  // [128]
    const float* __restrict__ Wih1,  // [128, 32]
    const float* __restrict__ Whh1,  // [128, 32]
    const float* __restrict__ bih1,  // [128]
    const float* __restrict__ bhh1,  // [128]
    const float* __restrict__ fcw,   // [32]
    const float* __restrict__ fcb,   // [1]
    const float* __restrict__ fc1w,  // [7]
    const float* __restrict__ fc1b,  // [1]
    float* __restrict__ out,         // [B]
    int B)
{
    const int tid  = threadIdx.x;
    const int lane = tid & 63;
    const int wave = tid >> 6;
    const int col  = lane & 15;          // C col / A row m
    const int rg   = lane >> 4;          // C rows rg*4..+3 / A k-chunk rg*8..+7
    const int seq_base = (blockIdx.x * 4 + wave) * 16;

    // [mat][nt][lane][8 halves]: mat 0 = Whh0, 1 = Wih1, 2 = Whh1
    __shared__ __align__(16) _Float16 ldsW[3][8][64][8];      // 24576 B
    __shared__ __align__(16) _Float16 ldsh[4][16 * LSTRIDE];  //  5120 B
    __shared__ __align__(16) float    ldsx[4][TSTEPS * 16];   //  1792 B

    // ---- stage weight fragments to LDS (block-shared, once) --------------
    // frag element [m][nt][ln][j] = sc(n) * W[n = nt*16+(ln&15)][k=(ln>>4)*8+j]
    {
        const float* Wsrc[3] = {Whh0, Wih1, Whh1};
#pragma unroll
        for (int m = 0; m < 3; ++m) {
#pragma unroll
            for (int f = 0; f < 2; ++f) {
                const int idx = tid * 2 + f;          // 0..511
                const int nt = idx >> 6, ln = idx & 63;
                const int n  = nt * 16 + (ln & 15);
                const int k0 = (ln >> 4) * 8;
                const float sc = ((n >> 5) == 2) ? (2.0f * LOG2E) : (-LOG2E);
                const float* s = Wsrc[m] + n * HID + k0;
                half8 fr;
#pragma unroll
                for (int j = 0; j < 8; ++j) fr[j] = (_Float16)(sc * s[j]);
                *(half8*)&ldsW[m][nt][ln][0] = fr;
            }
        }
    }

    // ---- stage x: 112 contiguous floats per wave -> transposed [t][m] ----
#pragma unroll
    for (int e = lane; e < TSTEPS * 16; e += 64) {
        const int s = e / TSTEPS;
        const int tt = e - s * TSTEPS;
        ldsx[wave][tt * 16 + s] = xin[seq_base * TSTEPS + e];
    }

    // ---- per-lane bias / rank-1 coefficients (VGPR-resident, 24 regs) ----
    float b0s[8], b1s[8], wx[8];
#pragma unroll
    for (int nt = 0; nt < 8; ++nt) {
        const int n = nt * 16 + col;
        const float sc = ((n >> 5) == 2) ? (2.0f * LOG2E) : (-LOG2E);
        b0s[nt] = sc * (bih0[n] + bhh0[n]);
        b1s[nt] = sc * (bih1[n] + bhh1[n]);
        wx[nt]  = sc * Wih0[n];
    }
    const float fcw_l0 = fcw[col];
    const float fcw_l1 = fcw[16 + col];

    __syncthreads();   // weight staging visible to all waves

    const _Float16* wbase = &ldsW[0][0][lane][0];   // frag (m,nt) at +((m*8+nt)*512) halves
    _Float16* hl = &ldsh[wave][0];

    half8 Ah1 = {};      // h1 in A-layout (zero at t=0)
    half8 Ah2 = {};      // h2 in A-layout
    float c1[2][4] = {}, c2[2][4] = {};  // prescaled: cs = 2*log2e*c
    float facc[4] = {0.f, 0.f, 0.f, 0.f};

    for (int t = 0; t < TSTEPS; ++t) {
        const floatx4 xr = *(const floatx4*)&ldsx[wave][t * 16 + rg * 4];

        // -------- layer 0: gates = (bias + x*Wih0) + h1_prev @ Whh0^T -----
        floatx4 g0[8];
#pragma unroll
        for (int nt = 0; nt < 8; ++nt) {
            const half8 w = *(const half8*)(wbase + nt * 512);
            floatx4 c;
#pragma unroll
            for (int r = 0; r < 4; ++r) c[r] = fmaf(wx[nt], xr[r], b0s[nt]);
            g0[nt] = __builtin_amdgcn_mfma_f32_16x16x32_f16(Ah1, w, c, 0, 0, 0);
        }

        // epilogue 0: cell update (prescaled cs), write h1_new to LDS
#pragma unroll
        for (int q = 0; q < 2; ++q) {
#pragma unroll
            for (int r = 0; r < 4; ++r) {
                const float ii = sigm_pre(g0[0 + q][r]);
                const float ff = sigm_pre(g0[2 + q][r]);
                const float gg = tanh_pre_g(g0[4 + q][r]);   // 2L*tanh(g)
                const float oo = sigm_pre(g0[6 + q][r]);
                const float cs = ff * c1[q][r] + ii * gg;    // = 2L*c
                c1[q][r] = cs;
                const float h = oo * tanh_pre(cs);           // tanh(c)
                hl[(rg * 4 + r) * LSTRIDE + q * 16 + col] = (_Float16)h;
            }
        }
        Ah1 = *(const half8*)&hl[col * LSTRIDE + rg * 8];

        // -------- layer 1: gates = bias + h1_new @ Wih1^T + h2_prev @ Whh1^T
        floatx4 g1[8];
#pragma unroll
        for (int nt = 0; nt < 8; ++nt) {
            const half8 wa = *(const half8*)(wbase + (8 + nt) * 512);
            const half8 wb = *(const half8*)(wbase + (16 + nt) * 512);
            floatx4 c = {b1s[nt], b1s[nt], b1s[nt], b1s[nt]};
            c = __builtin_amdgcn_mfma_f32_16x16x32_f16(Ah1, wa, c, 0, 0, 0);
            g1[nt] = __builtin_amdgcn_mfma_f32_16x16x32_f16(Ah2, wb, c, 0, 0, 0);
        }

        // epilogue 1: cell update, fc partial, write h2_new to LDS (same area)
        const float f1t = fc1w[t];
        const float w0 = f1t * fcw_l0;
        const float w1 = f1t * fcw_l1;
#pragma unroll
        for (int q = 0; q < 2; ++q) {
            const float wq = q ? w1 : w0;
#pragma unroll
            for (int r = 0; r < 4; ++r) {
                const float ii = sigm_pre(g1[0 + q][r]);
                const float ff = sigm_pre(g1[2 + q][r]);
                const float gg = tanh_pre_g(g1[4 + q][r]);
                const float oo = sigm_pre(g1[6 + q][r]);
                const float cs = ff * c2[q][r] + ii * gg;
                c2[q][r] = cs;
                const float h = oo * tanh_pre(cs);
                facc[r] = fmaf(wq, h, facc[r]);
                hl[(rg * 4 + r) * LSTRIDE + q * 16 + col] = (_Float16)h;
            }
        }
        Ah2 = *(const half8*)&hl[col * LSTRIDE + rg * 8];
    }

    // ---- reduce fc partials across the 16 cols, add constant tail --------
#pragma unroll
    for (int r = 0; r < 4; ++r) {
        float v = facc[r];
        v += __shfl_xor(v, 1);
        v += __shfl_xor(v, 2);
        v += __shfl_xor(v, 4);
        v += __shfl_xor(v, 8);
        facc[r] = v;
    }
    float sum_f1 = 0.f;
#pragma unroll
    for (int t = 0; t < TSTEPS; ++t) sum_f1 += fc1w[t];
    const float tail = fcb[0] * sum_f1 + fc1b[0];

    if (col == 0) {
#pragma unroll
        for (int r = 0; r < 4; ++r)
            out[seq_base + rg * 4 + r] = facc[r] + tail;
    }
}

extern "C" void kernel_launch(void* const* d_in, const int* in_sizes, int n_in,
                              void* d_out, int out_size, void* d_ws, size_t ws_size,
                              hipStream_t stream) {
    const float* xin  = (const float*)d_in[0];
    const float* Wih0 = (const float*)d_in[1];
    const float* Whh0 = (const float*)d_in[2];
    const float* bih0 = (const float*)d_in[3];
    const float* bhh0 = (const float*)d_in[4];
    const float* Wih1 = (const float*)d_in[5];
    const float* Whh1 = (const float*)d_in[6];
    const float* bih1 = (const float*)d_in[7];
    const float* bhh1 = (const float*)d_in[8];
    const float* fcw  = (const float*)d_in[9];
    const float* fcb  = (const float*)d_in[10];
    const float* fc1w = (const float*)d_in[11];
    const float* fc1b = (const float*)d_in[12];
    float* out = (float*)d_out;

    const int B = in_sizes[0] / TSTEPS;   // [B, T, F=1]
    const int grid = B / 64;              // 1 block = 4 waves = 64 sequences
    lstm2_mfma<<<grid, 256, 0, stream>>>(
        xin, Wih0, Whh0, bih0, bhh0, Wih1, Whh1, bih1, bhh1,
        fcw, fcb, fc1w, fc1b, out, B);
}